// Round 3
// baseline (356.898 us; speedup 1.0000x reference)
//
#include <hip/hip_runtime.h>
#include <stdint.h>

#define Bn 4
#define Cn 512
#define Tn 4096
#define Kn 256
#define Nall 768

typedef __attribute__((ext_vector_type(8))) short bf16x8;
typedef __attribute__((ext_vector_type(4))) float f32x4;

__device__ __forceinline__ unsigned short f2bf(float f) {
  union { float f; unsigned int u; } v; v.f = f;
  unsigned int r = v.u + 0x7fffu + ((v.u >> 16) & 1u);
  return (unsigned short)(r >> 16);
}

__device__ __forceinline__ void gload_lds16(const void* g, void* l) {
  auto gp = reinterpret_cast<const __attribute__((address_space(1))) unsigned int*>(
      reinterpret_cast<uintptr_t>(g));
  auto lp = reinterpret_cast<__attribute__((address_space(3))) unsigned int*>(
      static_cast<unsigned int>(reinterpret_cast<uintptr_t>(l)));
  __builtin_amdgcn_global_load_lds(gp, lp, 16, 0, 0);
}

__device__ __forceinline__ f32x4 mfma16(bf16x8 a, bf16x8 b, f32x4 c) {
  return __builtin_amdgcn_mfma_f32_16x16x32_bf16(a, b, c, 0, 0, 0);
}

// ---------------------------------------------------------------------------
// prep_x: fp32 passthrough copy into out rows [0,512) + transpose to x_t bf16 (B,T,C)
// ---------------------------------------------------------------------------
__global__ __launch_bounds__(256) void prep_x_kernel(const float* __restrict__ x,
    float* __restrict__ out, unsigned short* __restrict__ xt) {
  const int tt = blockIdx.x, cc = blockIdx.y, b = blockIdx.z;
  __shared__ unsigned short tile[64][66];
  const int tid = threadIdx.x;
#pragma unroll
  for (int e = 0; e < 4; ++e) {
    int f = e * 256 + tid;
    int row = f >> 4, c4 = f & 15;
    size_t gi = ((size_t)(b * Cn + cc * 64 + row)) * Tn + tt * 64 + c4 * 4;
    float4 v = *(const float4*)(x + gi);
    size_t go = ((size_t)(b * Nall + cc * 64 + row)) * Tn + tt * 64 + c4 * 4;
    *(float4*)(out + go) = v;
    tile[row][c4 * 4 + 0] = f2bf(v.x);
    tile[row][c4 * 4 + 1] = f2bf(v.y);
    tile[row][c4 * 4 + 2] = f2bf(v.z);
    tile[row][c4 * 4 + 3] = f2bf(v.w);
  }
  __syncthreads();
#pragma unroll
  for (int e = 0; e < 2; ++e) {
    int f = e * 256 + tid;
    int trow = f >> 3, cv = f & 7;
    bf16x8 vv;
#pragma unroll
    for (int j = 0; j < 8; ++j) vv[j] = (short)tile[cv * 8 + j][trow];
    *(bf16x8*)(xt + ((size_t)(b * Tn) + tt * 64 + trow) * Cn + cc * 64 + cv * 8) = vv;
  }
}

// ---------------------------------------------------------------------------
// prep_w: W^T bf16 (768 x 512); bias concat
// ---------------------------------------------------------------------------
__global__ __launch_bounds__(256) void prep_w_kernel(const float* __restrict__ Wq,
    const float* __restrict__ Wk, const float* __restrict__ Wv,
    const float* __restrict__ bq, const float* __restrict__ bk, const float* __restrict__ bv,
    unsigned short* __restrict__ wt, float* __restrict__ bias) {
  int idx = blockIdx.x * 256 + threadIdx.x;
  int n = idx >> 9, c = idx & 511;
  const float* W = (n < 256) ? Wq : ((n < 512) ? Wk : Wv);
  wt[idx] = f2bf(W[c * 256 + (n & 255)]);
  if (idx < Nall) {
    const float* bb = (idx < 256) ? bq : ((idx < 512) ? bk : bv);
    bias[idx] = bb[idx & 255];
  }
}

// ---------------------------------------------------------------------------
// qkv_gemm: 128x128 tile, BK=32, m97 structure (unchanged).
// ---------------------------------------------------------------------------
__global__ __launch_bounds__(256) void qkv_gemm_kernel(const unsigned short* __restrict__ xt,
    const unsigned short* __restrict__ wt, const float* __restrict__ bias,
    unsigned short* __restrict__ qb, unsigned short* __restrict__ kb,
    unsigned short* __restrict__ vt) {
  const int t0 = blockIdx.x * 128, n0 = blockIdx.y * 128, b = blockIdx.z;
  __shared__ char at[8192];
  __shared__ char bt[8192];
  const int tid = threadIdx.x, w = tid >> 6, lane = tid & 63, g = lane >> 4, lr = lane & 15;
  const int wm = w >> 1, wn = w & 1;
  f32x4 acc[4][4];
#pragma unroll
  for (int i = 0; i < 4; ++i)
#pragma unroll
    for (int j = 0; j < 4; ++j) acc[i][j] = (f32x4){0.f, 0.f, 0.f, 0.f};

  const unsigned short* xtp = xt + ((size_t)b * Tn + t0) * Cn;
  for (int c0 = 0; c0 < Cn; c0 += 32) {
    __syncthreads();
#pragma unroll
    for (int i = 0; i < 2; ++i) {
      int off = i * 4096 + w * 1024 + lane * 16;
      int row = off >> 6, col = off & 63;
      gload_lds16(xtp + (size_t)row * Cn + c0 + (col >> 1), at + i * 4096 + w * 1024);
      gload_lds16(wt + (size_t)(n0 + row) * Cn + c0 + (col >> 1), bt + i * 4096 + w * 1024);
    }
    __syncthreads();
    bf16x8 af[4], bfr[4];
#pragma unroll
    for (int mt = 0; mt < 4; ++mt)
      af[mt] = *(const bf16x8*)(at + (wm * 64 + mt * 16 + lr) * 64 + g * 16);
#pragma unroll
    for (int nt = 0; nt < 4; ++nt)
      bfr[nt] = *(const bf16x8*)(bt + (wn * 64 + nt * 16 + lr) * 64 + g * 16);
#pragma unroll
    for (int mt = 0; mt < 4; ++mt)
#pragma unroll
      for (int nt = 0; nt < 4; ++nt)
        acc[mt][nt] = mfma16(af[mt], bfr[nt], acc[mt][nt]);
  }
#pragma unroll
  for (int nt = 0; nt < 4; ++nt) {
    int n = n0 + wn * 64 + nt * 16 + lr;
    float bval = bias[n];
#pragma unroll
    for (int mt = 0; mt < 4; ++mt) {
#pragma unroll
      for (int r = 0; r < 4; ++r) {
        int t = t0 + wm * 64 + mt * 16 + g * 4 + r;
        unsigned short h = f2bf(acc[mt][nt][r] + bval);
        if (n < 256) {
          qb[((size_t)(b * Tn) + t) * Kn + n] = h;
        } else if (n < 512) {
          int nc = n - 256;
          kb[((size_t)(b * Tn) + t) * Kn + (nc ^ ((t & 7) << 3))] = h;
        } else {
          int vc = n - 512;
          int tl = t & 63;
          vt[((size_t)(b * Kn) + vc) * Tn + (t & ~63) + (tl ^ ((vc & 7) << 3))] = h;
        }
      }
    }
  }
}

// ---------------------------------------------------------------------------
// attn: split-KV flash causal attention.
// Work item = (b, qtile t of 64 rows, chunk c of <=16 s-tiles). 160 items/batch,
// 640 blocks, each <=16 steps of BS=64. Blocks covering a full row (t<16)
// normalize and write out directly; others write unnormalized partial o (fp32)
// + (m,l) in base-2 domain to po/ml (576 slots, t>=16 only).
// ---------------------------------------------------------------------------
__global__ __launch_bounds__(256) void attn_kernel(const unsigned short* __restrict__ qb,
    const unsigned short* __restrict__ kb, const unsigned short* __restrict__ vt,
    float* __restrict__ po, float* __restrict__ ml, float* __restrict__ out) {
  // XCD-aware remap: batch b -> XCD pair {2b, 2b+1}
  const int wg = blockIdx.x;
  const int b = (wg >> 1) & 3;
  const int item = ((wg >> 3) << 1) | (wg & 1);
  // item -> (qtile t, chunk c); pre16 = slot prefix among t>=16 tiles
  int i = item, t = 0, c = 0, pre16 = 0;
  for (t = 0; t < 64; ++t) {
    int cnt = (t >> 4) + 1;
    if (i < cnt) { c = i; break; }
    i -= cnt;
    if (t >= 16) pre16 += cnt;
  }
  const bool direct = (t < 16);          // single-chunk row: no partials needed
  const int slot = b * 144 + pre16 + c;
  const int qt0 = t * 64;
  const int sb = c * 16, se = min(sb + 16, t + 1);

  __shared__ char kbuf[32768];
  __shared__ char vbuf[32768];
  __shared__ char pbuf[8192];
  const int tid = threadIdx.x, w = tid >> 6, lane = tid & 63, g = lane >> 4, lr = lane & 15;
  const float SCL = 0.09016844005555521f;   // log2(e)/sqrt(256)

  const unsigned short* qrow = qb + ((size_t)(b * Tn) + qt0 + w * 16 + lr) * Kn;
  bf16x8 qf[8];
#pragma unroll
  for (int kc = 0; kc < 8; ++kc) qf[kc] = *(const bf16x8*)(qrow + kc * 32 + g * 8);

  f32x4 o[16];
#pragma unroll
  for (int nt = 0; nt < 16; ++nt) o[nt] = (f32x4){0.f, 0.f, 0.f, 0.f};
  float m2[4], lsum[4];
#pragma unroll
  for (int r = 0; r < 4; ++r) { m2[r] = -1e30f; lsum[r] = 0.f; }

  const unsigned short* kbp = kb + (size_t)(b * Tn) * Kn;
  const unsigned short* vtp = vt + (size_t)(b * Kn) * Tn;
  char* pbw = pbuf + w * 2048;   // wave-private P [16][64] bf16, swizzled

  for (int s = sb; s < se; ++s) {
    const int s0 = s * 64;
    __syncthreads();   // prev-step kbuf/vbuf reads complete
#pragma unroll
    for (int i2 = 0; i2 < 8; ++i2) {
      int off = i2 * 4096 + w * 1024 + lane * 16;
      { int row = off >> 9, col = off & 511;
        gload_lds16(kbp + (size_t)(s0 + row) * Kn + (col >> 1), kbuf + i2 * 4096 + w * 1024); }
      { int row = off >> 7, col = off & 127;
        gload_lds16(vtp + (size_t)row * Tn + s0 + (col >> 1), vbuf + i2 * 4096 + w * 1024); }
    }
    __syncthreads();   // staging drained

    // QK^T : S[16q][64s]
    f32x4 sfr[4];
#pragma unroll
    for (int ct = 0; ct < 4; ++ct) sfr[ct] = (f32x4){0.f, 0.f, 0.f, 0.f};
#pragma unroll
    for (int kc = 0; kc < 8; ++kc) {
#pragma unroll
      for (int ct = 0; ct < 4; ++ct) {
        int srow = ct * 16 + lr;
        bf16x8 kf = *(const bf16x8*)(kbuf + srow * 512 +
                                     ((kc * 64 + g * 16) ^ ((srow & 7) << 4)));
        sfr[ct] = mfma16(qf[kc], kf, sfr[ct]);
      }
    }

    // online softmax (base-2)
    float sv[4][4];
    const bool diag = (s0 == qt0);
#pragma unroll
    for (int ct = 0; ct < 4; ++ct)
#pragma unroll
      for (int r = 0; r < 4; ++r) {
        float v = sfr[ct][r] * SCL;
        if (diag) {
          int trow = qt0 + w * 16 + g * 4 + r;
          int scol = s0 + ct * 16 + lr;
          if (scol > trow) v = -1e30f;
        }
        sv[ct][r] = v;
      }
    float mt_[4];
#pragma unroll
    for (int r = 0; r < 4; ++r)
      mt_[r] = fmaxf(fmaxf(sv[0][r], sv[1][r]), fmaxf(sv[2][r], sv[3][r]));
#pragma unroll
    for (int d = 1; d < 16; d <<= 1)
#pragma unroll
      for (int r = 0; r < 4; ++r)
        mt_[r] = fmaxf(mt_[r], __shfl_xor(mt_[r], d, 64));
    float al[4], rs[4];
#pragma unroll
    for (int r = 0; r < 4; ++r) {
      float mn = fmaxf(m2[r], mt_[r]);
      al[r] = __builtin_amdgcn_exp2f(m2[r] - mn);
      m2[r] = mn;
      rs[r] = 0.f;
    }
    unsigned short ph[4][4];
#pragma unroll
    for (int ct = 0; ct < 4; ++ct)
#pragma unroll
      for (int r = 0; r < 4; ++r) {
        float p = __builtin_amdgcn_exp2f(sv[ct][r] - m2[r]);
        rs[r] += p;
        ph[ct][r] = f2bf(p);
      }
#pragma unroll
    for (int d = 1; d < 16; d <<= 1)
#pragma unroll
      for (int r = 0; r < 4; ++r)
        rs[r] += __shfl_xor(rs[r], d, 64);
#pragma unroll
    for (int r = 0; r < 4; ++r) lsum[r] = lsum[r] * al[r] + rs[r];
#pragma unroll
    for (int nt = 0; nt < 16; ++nt)
#pragma unroll
      for (int r = 0; r < 4; ++r) o[nt][r] *= al[r];

    // P -> wave-private pbuf (no barrier needed; disjoint from kbuf/vbuf)
#pragma unroll
    for (int ct = 0; ct < 4; ++ct)
#pragma unroll
      for (int r = 0; r < 4; ++r) {
        int row = g * 4 + r;
        int colb = (ct * 16 + lr) * 2;
        *(unsigned short*)(pbw + row * 128 + (colb ^ ((row & 7) << 4))) = ph[ct][r];
      }
    bf16x8 pa[2];
#pragma unroll
    for (int kc2 = 0; kc2 < 2; ++kc2)
      pa[kc2] = *(const bf16x8*)(pbw + lr * 128 +
                                 ((kc2 * 64 + g * 16) ^ ((lr & 7) << 4)));
#pragma unroll
    for (int nt = 0; nt < 16; ++nt) {
      int vrow = nt * 16 + lr;
#pragma unroll
      for (int kc2 = 0; kc2 < 2; ++kc2) {
        bf16x8 vf = *(const bf16x8*)(vbuf + vrow * 128 +
                                     ((kc2 * 64 + g * 16) ^ ((vrow & 7) << 4)));
        o[nt] = mfma16(pa[kc2], vf, o[nt]);
      }
    }
  }

  if (direct) {
    // whole causal row processed here: normalize and write final output
    float inv[4];
#pragma unroll
    for (int r = 0; r < 4; ++r) inv[r] = 1.0f / lsum[r];
    float* outp = out + ((size_t)(b * Nall) + 512) * Tn;
#pragma unroll
    for (int nt = 0; nt < 16; ++nt)
#pragma unroll
      for (int r = 0; r < 4; ++r)
        outp[(size_t)(nt * 16 + lr) * Tn + qt0 + w * 16 + g * 4 + r] = o[nt][r] * inv[r];
  } else {
    float* pob = po + (size_t)slot * 16384;
#pragma unroll
    for (int nt = 0; nt < 16; ++nt)
#pragma unroll
      for (int r = 0; r < 4; ++r)
        pob[(w * 16 + g * 4 + r) * 256 + nt * 16 + lr] = o[nt][r];
    if (lr == 0) {
#pragma unroll
      for (int r = 0; r < 4; ++r) {
        ml[(size_t)slot * 128 + w * 16 + g * 4 + r] = m2[r];
        ml[(size_t)slot * 128 + 64 + w * 16 + g * 4 + r] = lsum[r];
      }
    }
  }
}

// ---------------------------------------------------------------------------
// merge: per (qtile t>=16, batch): combine nc partials, normalize, write.
// ---------------------------------------------------------------------------
__global__ __launch_bounds__(256) void merge_kernel(const float* __restrict__ po,
    const float* __restrict__ ml, float* __restrict__ out) {
  const int t = blockIdx.x + 16, b = blockIdx.y, n = threadIdx.x;
  const int nc = (t >> 4) + 1;
  int pre16 = 0;
  for (int u = 16; u < t; ++u) pre16 += (u >> 4) + 1;
  const int slot0 = b * 144 + pre16;

  float* outp = out + ((size_t)(b * Nall + 512) + n) * Tn + t * 64;
  for (int r4 = 0; r4 < 16; ++r4) {
    float4 vv;
#pragma unroll
    for (int j = 0; j < 4; ++j) {
      int r = r4 * 4 + j;
      float M = -1e30f;
      for (int cc = 0; cc < nc; ++cc)
        M = fmaxf(M, ml[(size_t)(slot0 + cc) * 128 + r]);
      float L = 0.f, val = 0.f;
      for (int cc = 0; cc < nc; ++cc) {
        float mw = __builtin_amdgcn_exp2f(ml[(size_t)(slot0 + cc) * 128 + r] - M);
        L += ml[(size_t)(slot0 + cc) * 128 + 64 + r] * mw;
        val += po[(size_t)(slot0 + cc) * 16384 + r * 256 + n] * mw;
      }
      vv[j] = val / L;
    }
    *(float4*)(outp + r4 * 4) = vv;
  }
}

// ---------------------------------------------------------------------------
extern "C" void kernel_launch(void* const* d_in, const int* in_sizes, int n_in,
                              void* d_out, int out_size, void* d_ws, size_t ws_size,
                              hipStream_t stream) {
  const float* x  = (const float*)d_in[0];
  const float* Wq = (const float*)d_in[1];
  const float* bq = (const float*)d_in[2];
  const float* Wk = (const float*)d_in[3];
  const float* bk = (const float*)d_in[4];
  const float* Wv = (const float*)d_in[5];
  const float* bv = (const float*)d_in[6];
  float* out = (float*)d_out;
  char* ws = (char*)d_ws;

  // layout (63,209,472 B total — fits a 64 MB scratch):
  // qb|kb|vt persistent through attn; xt/wt/bias dead after gemm and
  // overlapped by the split-KV partial buffers po/ml.
  unsigned short* qb = (unsigned short*)(ws);                 //  8,388,608
  unsigned short* kb = (unsigned short*)(ws + 8388608);       //  8,388,608
  unsigned short* vt = (unsigned short*)(ws + 16777216);      //  8,388,608
  unsigned short* xt = (unsigned short*)(ws + 25165824);      // 16,777,216 (dead after gemm)
  unsigned short* wt = (unsigned short*)(ws + 41943040);      //    786,432 (dead after gemm)
  float*        bias = (float*)(ws + 42729472);               //      3,072 (dead after gemm)
  float*          po = (float*)(ws + 25165824);               // 37,748,736 = 576 x 64KB (overlaps xt/wt/bias)
  float*          mlb = (float*)(ws + 62914560);              //    294,912 (ends 63,209,472)

  prep_w_kernel<<<1536, 256, 0, stream>>>(Wq, Wk, Wv, bq, bk, bv, wt, bias);
  prep_x_kernel<<<dim3(64, 8, 4), 256, 0, stream>>>(x, out, xt);
  qkv_gemm_kernel<<<dim3(32, 6, 4), 256, 0, stream>>>(xt, wt, bias, qb, kb, vt);
  attn_kernel<<<640, 256, 0, stream>>>(qb, kb, vt, po, mlb, out);
  merge_kernel<<<dim3(48, 4), 256, 0, stream>>>(po, mlb, out);
}

// Round 4
// 278.560 us; speedup vs baseline: 1.2812x; 1.2812x over previous
//
#include <hip/hip_runtime.h>
#include <stdint.h>

#define Bn 4
#define Cn 512
#define Tn 4096
#define Kn 256
#define Nall 768

typedef __attribute__((ext_vector_type(8))) short bf16x8;
typedef __attribute__((ext_vector_type(4))) float f32x4;

__device__ __forceinline__ unsigned short f2bf(float f) {
  union { float f; unsigned int u; } v; v.f = f;
  unsigned int r = v.u + 0x7fffu + ((v.u >> 16) & 1u);
  return (unsigned short)(r >> 16);
}

__device__ __forceinline__ void gload_lds16(const void* g, void* l) {
  auto gp = reinterpret_cast<const __attribute__((address_space(1))) unsigned int*>(
      reinterpret_cast<uintptr_t>(g));
  auto lp = reinterpret_cast<__attribute__((address_space(3))) unsigned int*>(
      static_cast<unsigned int>(reinterpret_cast<uintptr_t>(l)));
  __builtin_amdgcn_global_load_lds(gp, lp, 16, 0, 0);
}

__device__ __forceinline__ f32x4 mfma16(bf16x8 a, bf16x8 b, f32x4 c) {
  return __builtin_amdgcn_mfma_f32_16x16x32_bf16(a, b, c, 0, 0, 0);
}

// ---------------------------------------------------------------------------
// prep_x: fp32 passthrough copy into out rows [0,512) + transpose to x_t bf16 (B,T,C)
// ---------------------------------------------------------------------------
__global__ __launch_bounds__(256) void prep_x_kernel(const float* __restrict__ x,
    float* __restrict__ out, unsigned short* __restrict__ xt) {
  const int tt = blockIdx.x, cc = blockIdx.y, b = blockIdx.z;
  __shared__ unsigned short tile[64][66];
  const int tid = threadIdx.x;
#pragma unroll
  for (int e = 0; e < 4; ++e) {
    int f = e * 256 + tid;
    int row = f >> 4, c4 = f & 15;
    size_t gi = ((size_t)(b * Cn + cc * 64 + row)) * Tn + tt * 64 + c4 * 4;
    float4 v = *(const float4*)(x + gi);
    size_t go = ((size_t)(b * Nall + cc * 64 + row)) * Tn + tt * 64 + c4 * 4;
    *(float4*)(out + go) = v;
    tile[row][c4 * 4 + 0] = f2bf(v.x);
    tile[row][c4 * 4 + 1] = f2bf(v.y);
    tile[row][c4 * 4 + 2] = f2bf(v.z);
    tile[row][c4 * 4 + 3] = f2bf(v.w);
  }
  __syncthreads();
#pragma unroll
  for (int e = 0; e < 2; ++e) {
    int f = e * 256 + tid;
    int trow = f >> 3, cv = f & 7;
    bf16x8 vv;
#pragma unroll
    for (int j = 0; j < 8; ++j) vv[j] = (short)tile[cv * 8 + j][trow];
    *(bf16x8*)(xt + ((size_t)(b * Tn) + tt * 64 + trow) * Cn + cc * 64 + cv * 8) = vv;
  }
}

// ---------------------------------------------------------------------------
// prep_w: W^T bf16 (768 x 512); bias concat
// ---------------------------------------------------------------------------
__global__ __launch_bounds__(256) void prep_w_kernel(const float* __restrict__ Wq,
    const float* __restrict__ Wk, const float* __restrict__ Wv,
    const float* __restrict__ bq, const float* __restrict__ bk, const float* __restrict__ bv,
    unsigned short* __restrict__ wt, float* __restrict__ bias) {
  int idx = blockIdx.x * 256 + threadIdx.x;
  int n = idx >> 9, c = idx & 511;
  const float* W = (n < 256) ? Wq : ((n < 512) ? Wk : Wv);
  wt[idx] = f2bf(W[c * 256 + (n & 255)]);
  if (idx < Nall) {
    const float* bb = (idx < 256) ? bq : ((idx < 512) ? bk : bv);
    bias[idx] = bb[idx & 255];
  }
}

// ---------------------------------------------------------------------------
// qkv_gemm: 128x128 tile, BK=32, m97 structure (unchanged).
// ---------------------------------------------------------------------------
__global__ __launch_bounds__(256) void qkv_gemm_kernel(const unsigned short* __restrict__ xt,
    const unsigned short* __restrict__ wt, const float* __restrict__ bias,
    unsigned short* __restrict__ qb, unsigned short* __restrict__ kb,
    unsigned short* __restrict__ vt) {
  const int t0 = blockIdx.x * 128, n0 = blockIdx.y * 128, b = blockIdx.z;
  __shared__ char at[8192];
  __shared__ char bt[8192];
  const int tid = threadIdx.x, w = tid >> 6, lane = tid & 63, g = lane >> 4, lr = lane & 15;
  const int wm = w >> 1, wn = w & 1;
  f32x4 acc[4][4];
#pragma unroll
  for (int i = 0; i < 4; ++i)
#pragma unroll
    for (int j = 0; j < 4; ++j) acc[i][j] = (f32x4){0.f, 0.f, 0.f, 0.f};

  const unsigned short* xtp = xt + ((size_t)b * Tn + t0) * Cn;
  for (int c0 = 0; c0 < Cn; c0 += 32) {
    __syncthreads();
#pragma unroll
    for (int i = 0; i < 2; ++i) {
      int off = i * 4096 + w * 1024 + lane * 16;
      int row = off >> 6, col = off & 63;
      gload_lds16(xtp + (size_t)row * Cn + c0 + (col >> 1), at + i * 4096 + w * 1024);
      gload_lds16(wt + (size_t)(n0 + row) * Cn + c0 + (col >> 1), bt + i * 4096 + w * 1024);
    }
    __syncthreads();
    bf16x8 af[4], bfr[4];
#pragma unroll
    for (int mt = 0; mt < 4; ++mt)
      af[mt] = *(const bf16x8*)(at + (wm * 64 + mt * 16 + lr) * 64 + g * 16);
#pragma unroll
    for (int nt = 0; nt < 4; ++nt)
      bfr[nt] = *(const bf16x8*)(bt + (wn * 64 + nt * 16 + lr) * 64 + g * 16);
#pragma unroll
    for (int mt = 0; mt < 4; ++mt)
#pragma unroll
      for (int nt = 0; nt < 4; ++nt)
        acc[mt][nt] = mfma16(af[mt], bfr[nt], acc[mt][nt]);
  }
#pragma unroll
  for (int nt = 0; nt < 4; ++nt) {
    int n = n0 + wn * 64 + nt * 16 + lr;
    float bval = bias[n];
#pragma unroll
    for (int mt = 0; mt < 4; ++mt) {
#pragma unroll
      for (int r = 0; r < 4; ++r) {
        int t = t0 + wm * 64 + mt * 16 + g * 4 + r;
        unsigned short h = f2bf(acc[mt][nt][r] + bval);
        if (n < 256) {
          qb[((size_t)(b * Tn) + t) * Kn + n] = h;
        } else if (n < 512) {
          int nc = n - 256;
          kb[((size_t)(b * Tn) + t) * Kn + (nc ^ ((t & 7) << 3))] = h;
        } else {
          int vc = n - 512;
          int tl = t & 63;
          vt[((size_t)(b * Kn) + vc) * Tn + (t & ~63) + (tl ^ ((vc & 7) << 3))] = h;
        }
      }
    }
  }
}

// ---------------------------------------------------------------------------
// attn: split-KV flash causal attention, 8 waves x 128 q-rows, BS=64,
// K/V double-buffered in LDS with ONE barrier per step (stage for s+1 issued
// before computing s; the barrier's vmcnt(0) drain lands after compute).
// 80 chunks/batch (<=16 steps), scrambled for balance. t<8 rows are complete
// -> direct normalized write; else fp32 partials (po) + (m,l) base-2 (ml).
// LDS: 2x32K (K) + 2x32K (V) + 16K (P) = 144 KB -> 1 block/CU, 8 waves.
// ---------------------------------------------------------------------------
#define STAGE(s_, par_) do {                                                   \
    const int s0_ = (s_) * 64;                                                 \
    char* kd_ = kbase + (par_) * 32768;                                        \
    char* vd_ = vbase + (par_) * 32768;                                        \
    _Pragma("unroll")                                                          \
    for (int i2 = 0; i2 < 4; ++i2) {                                           \
      int off_ = i2 * 8192 + tid * 16;                                         \
      int krow_ = off_ >> 9, kcol_ = off_ & 511;                               \
      gload_lds16(kbp + (size_t)(s0_ + krow_) * Kn + (kcol_ >> 1), kd_ + off_);\
      int vrow_ = off_ >> 7, vcol_ = off_ & 127;                               \
      gload_lds16(vtp + (size_t)vrow_ * Tn + s0_ + (vcol_ >> 1), vd_ + off_);  \
    }                                                                          \
  } while (0)

__global__ __launch_bounds__(512) void attn_kernel(const unsigned short* __restrict__ qb,
    const unsigned short* __restrict__ kb, const unsigned short* __restrict__ vt,
    float* __restrict__ po, float* __restrict__ ml, float* __restrict__ out) {
  // batch -> XCD pair; chunk order scrambled for load balance
  const int wg = blockIdx.x;
  const int b = (wg >> 1) & 3;
  int item = ((wg >> 3) << 1) | (wg & 1);     // [0,80)
  item = (item * 53) % 80;                    // bijective scramble
  int t = 0, c = 0, preP = 0, accum = 0;
  for (t = 0; t < 32; ++t) {
    int cnt = (t + 8) >> 3;                   // ceil((t+1)/8)
    if (item < accum + cnt) { c = item - accum; break; }
    accum += cnt;
    if (t >= 8) preP += cnt;
  }
  const bool direct = (t < 8);
  const int slot = b * 72 + preP + c;
  const int qt0 = t << 7;
  const int sb = c * 16, se = min(sb + 16, 2 * t + 2);

  __shared__ char smem[147456];
  char* kbase = smem;            // 2 x 32768
  char* vbase = smem + 65536;    // 2 x 32768
  char* pbuf  = smem + 131072;   // 8 waves x 2048
  const int tid = threadIdx.x, w = tid >> 6, lane = tid & 63, g = lane >> 4, lr = lane & 15;
  const float SCL = 0.09016844005555521f;   // log2(e)/sqrt(256)

  const unsigned short* kbp = kb + (size_t)(b * Tn) * Kn;
  const unsigned short* vtp = vt + (size_t)(b * Kn) * Tn;

  const unsigned short* qrow = qb + ((size_t)(b * Tn) + qt0 + w * 16 + lr) * Kn;
  bf16x8 qf[8];
#pragma unroll
  for (int kc = 0; kc < 8; ++kc) qf[kc] = *(const bf16x8*)(qrow + kc * 32 + g * 8);

  f32x4 o[16];
#pragma unroll
  for (int nt = 0; nt < 16; ++nt) o[nt] = (f32x4){0.f, 0.f, 0.f, 0.f};
  float m2[4], lsum[4];
#pragma unroll
  for (int r = 0; r < 4; ++r) { m2[r] = -1e30f; lsum[r] = 0.f; }
  char* pbw = pbuf + w * 2048;   // wave-private P [16][64] bf16, swizzled

  STAGE(sb, 0);
  __syncthreads();               // prologue drain
  int cur = 0;
  for (int s = sb; s < se; ++s) {
    const int s0 = s * 64;
    if (s + 1 < se) STAGE(s + 1, cur ^ 1);   // issue next tile BEFORE compute
    char* kcur = kbase + cur * 32768;
    char* vcur = vbase + cur * 32768;

    // QK^T : S[16q][64s] per wave
    f32x4 sfr[4];
#pragma unroll
    for (int ct = 0; ct < 4; ++ct) sfr[ct] = (f32x4){0.f, 0.f, 0.f, 0.f};
#pragma unroll
    for (int kc = 0; kc < 8; ++kc) {
#pragma unroll
      for (int ct = 0; ct < 4; ++ct) {
        int srow = ct * 16 + lr;
        bf16x8 kf = *(const bf16x8*)(kcur + srow * 512 +
                                     ((kc * 64 + g * 16) ^ ((srow & 7) << 4)));
        sfr[ct] = mfma16(qf[kc], kf, sfr[ct]);
      }
    }

    // online softmax (base-2)
    float sv[4][4];
    const bool diag = (s0 >= qt0);
#pragma unroll
    for (int ct = 0; ct < 4; ++ct)
#pragma unroll
      for (int r = 0; r < 4; ++r) {
        float v = sfr[ct][r] * SCL;
        if (diag) {
          int trow = qt0 + w * 16 + g * 4 + r;
          int scol = s0 + ct * 16 + lr;
          if (scol > trow) v = -1e30f;
        }
        sv[ct][r] = v;
      }
    float mt_[4];
#pragma unroll
    for (int r = 0; r < 4; ++r)
      mt_[r] = fmaxf(fmaxf(sv[0][r], sv[1][r]), fmaxf(sv[2][r], sv[3][r]));
#pragma unroll
    for (int d = 1; d < 16; d <<= 1)
#pragma unroll
      for (int r = 0; r < 4; ++r)
        mt_[r] = fmaxf(mt_[r], __shfl_xor(mt_[r], d, 64));
    float al[4], rs[4];
#pragma unroll
    for (int r = 0; r < 4; ++r) {
      float mn = fmaxf(m2[r], mt_[r]);
      al[r] = __builtin_amdgcn_exp2f(m2[r] - mn);
      m2[r] = mn;
      rs[r] = 0.f;
    }
    unsigned short ph[4][4];
#pragma unroll
    for (int ct = 0; ct < 4; ++ct)
#pragma unroll
      for (int r = 0; r < 4; ++r) {
        float p = __builtin_amdgcn_exp2f(sv[ct][r] - m2[r]);
        rs[r] += p;
        ph[ct][r] = f2bf(p);
      }
#pragma unroll
    for (int d = 1; d < 16; d <<= 1)
#pragma unroll
      for (int r = 0; r < 4; ++r)
        rs[r] += __shfl_xor(rs[r], d, 64);
#pragma unroll
    for (int r = 0; r < 4; ++r) lsum[r] = lsum[r] * al[r] + rs[r];
#pragma unroll
    for (int nt = 0; nt < 16; ++nt)
#pragma unroll
      for (int r = 0; r < 4; ++r) o[nt][r] *= al[r];

    // P -> wave-private pbuf, then PV
#pragma unroll
    for (int ct = 0; ct < 4; ++ct)
#pragma unroll
      for (int r = 0; r < 4; ++r) {
        int row = g * 4 + r;
        int colb = (ct * 16 + lr) * 2;
        *(unsigned short*)(pbw + row * 128 + (colb ^ ((row & 7) << 4))) = ph[ct][r];
      }
    bf16x8 pa[2];
#pragma unroll
    for (int kc2 = 0; kc2 < 2; ++kc2)
      pa[kc2] = *(const bf16x8*)(pbw + lr * 128 +
                                 ((kc2 * 64 + g * 16) ^ ((lr & 7) << 4)));
#pragma unroll
    for (int nt = 0; nt < 16; ++nt) {
      int vrow = nt * 16 + lr;
#pragma unroll
      for (int kc2 = 0; kc2 < 2; ++kc2) {
        bf16x8 vf = *(const bf16x8*)(vcur + vrow * 128 +
                                     ((kc2 * 64 + g * 16) ^ ((vrow & 7) << 4)));
        o[nt] = mfma16(pa[kc2], vf, o[nt]);
      }
    }

    __syncthreads();   // single drain: vmcnt(0) waits for stage issued this iter
    cur ^= 1;
  }

  if (direct) {
    float inv[4];
#pragma unroll
    for (int r = 0; r < 4; ++r) inv[r] = 1.0f / lsum[r];
    float* outp = out + ((size_t)(b * Nall) + 512) * Tn;
#pragma unroll
    for (int nt = 0; nt < 16; ++nt)
#pragma unroll
      for (int r = 0; r < 4; ++r)
        outp[(size_t)(nt * 16 + lr) * Tn + qt0 + w * 16 + g * 4 + r] = o[nt][r] * inv[r];
  } else {
    float* pob = po + (size_t)slot * 32768;
#pragma unroll
    for (int nt = 0; nt < 16; ++nt)
#pragma unroll
      for (int r = 0; r < 4; ++r)
        pob[(w * 16 + g * 4 + r) * 256 + nt * 16 + lr] = o[nt][r];
    if (lr == 0) {
#pragma unroll
      for (int r = 0; r < 4; ++r) {
        ml[(size_t)slot * 256 + w * 16 + g * 4 + r] = m2[r];
        ml[(size_t)slot * 256 + 128 + w * 16 + g * 4 + r] = lsum[r];
      }
    }
  }
}

// ---------------------------------------------------------------------------
// merge: per (tile t>=8, batch, 32-row group): hoist per-row merge scalars to
// LDS once, then stream po with coalesced float4 writes along t.
// ---------------------------------------------------------------------------
__global__ __launch_bounds__(256) void merge_kernel(const float* __restrict__ po,
    const float* __restrict__ ml, float* __restrict__ out) {
  const int tt = blockIdx.x + 8;           // tile [8,32)
  const int b = blockIdx.y, zg = blockIdx.z;  // row-group [0,4)
  const int nc = (tt + 8) >> 3;
  int preP = 0;
  for (int u = 8; u < tt; ++u) preP += (u + 8) >> 3;
  const int slot0 = b * 72 + preP;
  const int tid = threadIdx.x;

  __shared__ float wrow[32][4];
  if (tid < 32) {
    int r = zg * 32 + tid;
    float M = -1e30f;
    for (int cc = 0; cc < nc; ++cc)
      M = fmaxf(M, ml[(size_t)(slot0 + cc) * 256 + r]);
    float e[4], L = 0.f;
    for (int cc = 0; cc < nc; ++cc) {
      e[cc] = __builtin_amdgcn_exp2f(ml[(size_t)(slot0 + cc) * 256 + r] - M);
      L += ml[(size_t)(slot0 + cc) * 256 + 128 + r] * e[cc];
    }
    float linv = 1.0f / L;
    for (int cc = 0; cc < nc; ++cc) wrow[tid][cc] = e[cc] * linv;
  }
  __syncthreads();

  const int n = tid;   // v index
  float* outp = out + ((size_t)(b * Nall + 512 + n)) * Tn + tt * 128 + zg * 32;
  for (int r4 = 0; r4 < 8; ++r4) {
    float4 vv;
#pragma unroll
    for (int j = 0; j < 4; ++j) {
      int rl = r4 * 4 + j;          // row within group
      int rr = zg * 32 + rl;        // row within tile
      float val = 0.f;
      for (int cc = 0; cc < nc; ++cc)
        val += wrow[rl][cc] * po[(size_t)(slot0 + cc) * 32768 + rr * 256 + n];
      vv[j] = val;
    }
    *(float4*)(outp + r4 * 4) = vv;
  }
}

// ---------------------------------------------------------------------------
extern "C" void kernel_launch(void* const* d_in, const int* in_sizes, int n_in,
                              void* d_out, int out_size, void* d_ws, size_t ws_size,
                              hipStream_t stream) {
  const float* x  = (const float*)d_in[0];
  const float* Wq = (const float*)d_in[1];
  const float* bq = (const float*)d_in[2];
  const float* Wk = (const float*)d_in[3];
  const float* bk = (const float*)d_in[4];
  const float* Wv = (const float*)d_in[5];
  const float* bv = (const float*)d_in[6];
  float* out = (float*)d_out;
  char* ws = (char*)d_ws;

  // layout (63,209,472 B total — same proven footprint as round 3):
  unsigned short* qb = (unsigned short*)(ws);                 //  8,388,608
  unsigned short* kb = (unsigned short*)(ws + 8388608);       //  8,388,608
  unsigned short* vt = (unsigned short*)(ws + 16777216);      //  8,388,608
  unsigned short* xt = (unsigned short*)(ws + 25165824);      // 16,777,216 (dead after gemm)
  unsigned short* wt = (unsigned short*)(ws + 41943040);      //    786,432 (dead after gemm)
  float*        bias = (float*)(ws + 42729472);               //      3,072 (dead after gemm)
  float*          po = (float*)(ws + 25165824);               // 37,748,736 = 288 x 128KB (overlaps xt/wt/bias)
  float*          mlb = (float*)(ws + 62914560);              //    294,912 (ends 63,209,472)

  prep_w_kernel<<<1536, 256, 0, stream>>>(Wq, Wk, Wv, bq, bk, bv, wt, bias);
  prep_x_kernel<<<dim3(64, 8, 4), 256, 0, stream>>>(x, out, xt);
  qkv_gemm_kernel<<<dim3(32, 6, 4), 256, 0, stream>>>(xt, wt, bias, qb, kb, vt);
  attn_kernel<<<320, 512, 0, stream>>>(qb, kb, vt, po, mlb, out);
  merge_kernel<<<dim3(24, 4, 4), 256, 0, stream>>>(po, mlb, out);
}